// Round 6
// baseline (336.820 us; speedup 1.0000x reference)
//
#include <hip/hip_runtime.h>
#include <hip/hip_cooperative_groups.h>
#include <math.h>

namespace cg = cooperative_groups;

// Problem constants
constexpr int L = 4096;    // seq len
constexpr int D = 1024;    // d_model
constexpr int N = 16;      // hiddens per channel

// Fused (cooperative) config
constexpr int FNC = 64;         // chunks
constexpr int FT  = L / FNC;    // 64 steps per chunk
constexpr int FG  = 16;         // d-groups per chunk
constexpr int FDG = D / FG;     // 64 channels per block
constexpr int FNB = FNC * FG;   // 1024 blocks (4 per CU)

__device__ __forceinline__ float softplus_f(float v) {
    return fmaxf(v, 0.0f) + log1pf(expf(-fabsf(v)));
}

// ---------------------------------------------------------------------------
// Fused cooperative kernel: local scan -> grid sync -> chunk scan -> grid
// sync -> rescan+output. x staged into LDS ONCE and reused in phase 3.
// State layout s2[c][n][d] (float2), 8 MiB.
// ---------------------------------------------------------------------------
__global__ __launch_bounds__(256, 4) void k_fused(
    const float* __restrict__ x, const float* __restrict__ Delta,
    const float* __restrict__ A_re, const float* __restrict__ A_im,
    const float* __restrict__ B_re, const float* __restrict__ B_im,
    const float* __restrict__ C_re, const float* __restrict__ C_im,
    const float* __restrict__ Dp, float* __restrict__ out,
    float2* __restrict__ s2)
{
    cg::grid_group grid = cg::this_grid();
    __shared__ float xs[FT * FDG];        // 16 KiB x slice
    const int b  = blockIdx.x;
    const int c  = b >> 4;                // chunk
    const int dg = b & 15;                // d-group
    const int t  = threadIdx.x;

    // ---- stage x[cT.. ) x [dg*64 .. ) into LDS, float4-coalesced ----
    const float* xg = x + (size_t)c * FT * D + dg * FDG;
    #pragma unroll
    for (int it = 0; it < 4; ++it) {      // 4096 floats
        int f = t * 4 + it * 1024;
        int row = f >> 6, col = f & 63;
        *(float4*)&xs[row * FDG + col] =
            *(const float4*)(xg + (size_t)row * D + col);
    }

    // ---- per-thread params: thread owns (d = dg*64 + t/4, n = (t&3)*4+j) ----
    const int q = t & 3, dl = t >> 2;
    const int d = dg * FDG + dl;
    const float dt  = softplus_f(Delta[d]);
    float Lr[4], Li[4], Cr[4], Ci[4];
    {
        const int pidx = d * N + q * 4;
        float4 a0 = *(const float4*)(A_re + pidx);
        float4 a1 = *(const float4*)(A_im + pidx);
        float4 b0 = *(const float4*)(B_re + pidx);
        float4 b1 = *(const float4*)(B_im + pidx);
        float4 c0 = *(const float4*)(C_re + pidx);
        float4 c1 = *(const float4*)(C_im + pidx);
        const float ar[4] = {a0.x, a0.y, a0.z, a0.w};
        const float ai[4] = {a1.x, a1.y, a1.z, a1.w};
        const float br[4] = {b0.x, b0.y, b0.z, b0.w};
        const float bi[4] = {b1.x, b1.y, b1.z, b1.w};
        const float cr[4] = {c0.x, c0.y, c0.z, c0.w};
        const float ci[4] = {c1.x, c1.y, c1.z, c1.w};
        #pragma unroll
        for (int j = 0; j < 4; ++j) {
            float e  = expf(ar[j] * dt);
            float th = ai[j] * dt;
            Lr[j] = e * cosf(th);
            Li[j] = e * sinf(th);
            Cr[j] = dt * (cr[j] * br[j] - ci[j] * bi[j]);
            Ci[j] = dt * (cr[j] * bi[j] + ci[j] * br[j]);
        }
    }
    __syncthreads();

    // ---- phase 1: local scan, zero init ----
    float gr[4] = {0, 0, 0, 0}, gi[4] = {0, 0, 0, 0};
    #pragma unroll
    for (int i = 0; i < FT; ++i) {
        float xv = xs[i * FDG + dl];
        #pragma unroll
        for (int j = 0; j < 4; ++j) {
            float t2 = fmaf(-Li[j], gi[j], xv);
            float nr = fmaf(Lr[j], gr[j], t2);
            gi[j] = fmaf(Lr[j], gi[j], Li[j] * gr[j]);
            gr[j] = nr;
        }
    }
    #pragma unroll
    for (int j = 0; j < 4; ++j)
        s2[((size_t)c * N + q * 4 + j) * D + d] = make_float2(gr[j], gi[j]);

    grid.sync();

    // ---- phase 2: chunk-level scan, 16384 threads (blocks 0..63) ----
    const int pid = b * 256 + t;
    if (pid < N * D) {
        const int pd = pid & (D - 1);
        const int pn = pid >> 10;
        const float pdt = softplus_f(Delta[pd]);
        float e  = expf(A_re[pd * N + pn] * pdt);
        float th = A_im[pd * N + pn] * pdt;
        float lr = e * cosf(th), li = e * sinf(th);
        #pragma unroll
        for (int k = 0; k < 6; ++k) {     // Lam^64
            float nr = lr * lr - li * li;
            li = 2.0f * lr * li;
            lr = nr;
        }
        float cr = 0.0f, ci = 0.0f;
        for (int c0 = 0; c0 < FNC; c0 += 8) {
            float2 sv[8];
            #pragma unroll
            for (int u = 0; u < 8; ++u)
                sv[u] = s2[((size_t)(c0 + u) * N + pn) * D + pd];
            #pragma unroll
            for (int u = 0; u < 8; ++u) {
                s2[((size_t)(c0 + u) * N + pn) * D + pd] = make_float2(cr, ci);
                float nr = fmaf(lr, cr, fmaf(-li, ci, sv[u].x));
                ci = fmaf(lr, ci, fmaf(li, cr, sv[u].y));
                cr = nr;
            }
        }
    }

    grid.sync();

    // ---- phase 3: rescan from carry (x still in LDS), contract, store ----
    #pragma unroll
    for (int j = 0; j < 4; ++j) {
        float2 cv = s2[((size_t)c * N + q * 4 + j) * D + d];
        gr[j] = cv.x; gi[j] = cv.y;
    }
    const float dpv = Dp[d];
    float* og = out + (size_t)c * FT * D + dg * FDG;
    #pragma unroll
    for (int ib = 0; ib < FT / 4; ++ib) {
        float keep = 0.0f;
        #pragma unroll
        for (int u = 0; u < 4; ++u) {
            int i = ib * 4 + u;
            float xv = xs[i * FDG + dl];
            float acc = 0.0f;
            #pragma unroll
            for (int j = 0; j < 4; ++j) {
                float t2 = fmaf(-Li[j], gi[j], xv);
                float nr = fmaf(Lr[j], gr[j], t2);
                gi[j] = fmaf(Lr[j], gi[j], Li[j] * gr[j]);
                gr[j] = nr;
                acc = fmaf(Cr[j], gr[j], acc);
                acc = fmaf(-Ci[j], gi[j], acc);
            }
            acc += __shfl_xor(acc, 1);
            acc += __shfl_xor(acc, 2);
            acc = fmaf(dpv, xv, acc);
            keep = (q == u) ? acc : keep;
        }
        og[(size_t)(ib * 4 + q) * D + dl] = keep;   // all 64 lanes store
    }
}

// ---------------------------------------------------------------------------
// Fallback: proven round-5 4-kernel pipeline (NC=128), used only if the
// cooperative launch is rejected.
// ---------------------------------------------------------------------------
constexpr int BNC = 128;
constexpr int BT  = L / BNC;   // 32

__global__ __launch_bounds__(256) void k_pre(
    const float* __restrict__ Delta,
    const float* __restrict__ A_re, const float* __restrict__ A_im,
    const float* __restrict__ B_re, const float* __restrict__ B_im,
    const float* __restrict__ C_re, const float* __restrict__ C_im,
    float* __restrict__ PLr, float* __restrict__ PLi,
    float* __restrict__ PTr, float* __restrict__ PTi,
    float* __restrict__ PCr, float* __restrict__ PCi)
{
    const int tid = blockIdx.x * 256 + threadIdx.x;
    const int d = tid & (D - 1);
    const int n = tid >> 10;
    const int idx = d * N + n;
    const float dt = softplus_f(Delta[d]);
    float e  = expf(A_re[idx] * dt);
    float th = A_im[idx] * dt;
    float lr = e * cosf(th), li = e * sinf(th);
    float tr = lr, ti = li;
    #pragma unroll
    for (int k = 0; k < 5; ++k) {
        float nr = tr * tr - ti * ti;
        ti = 2.0f * tr * ti;
        tr = nr;
    }
    float br = B_re[idx], bi = B_im[idx];
    float cr = C_re[idx], ci = C_im[idx];
    PLr[tid] = lr; PLi[tid] = li;
    PTr[tid] = tr; PTi[tid] = ti;
    PCr[tid] = dt * (cr * br - ci * bi);
    PCi[tid] = dt * (cr * bi + ci * br);
}

__global__ __launch_bounds__(256, 4) void k_local(
    const float* __restrict__ x,
    const float* __restrict__ PLr, const float* __restrict__ PLi,
    float2* __restrict__ s2)
{
    __shared__ float xs[BT * 64];
    const int bc = blockIdx.x >> 4;
    const int dg = blockIdx.x & 15;
    const int tid = threadIdx.x;
    const float* xg = x + (size_t)bc * BT * D + dg * 64;
    #pragma unroll
    for (int it = 0; it < 2; ++it) {
        int f = tid * 4 + it * 1024;
        int row = f >> 6, col = f & 63;
        *(float4*)&xs[row * 64 + col] = *(const float4*)(xg + (size_t)row * D + col);
    }
    const int q = tid & 3, dl = tid >> 2;
    const int d = dg * 64 + dl;
    float Lr[4], Li[4];
    #pragma unroll
    for (int j = 0; j < 4; ++j) {
        int n = q * 4 + j;
        Lr[j] = PLr[n * D + d];
        Li[j] = PLi[n * D + d];
    }
    __syncthreads();
    float gr[4] = {0, 0, 0, 0}, gi[4] = {0, 0, 0, 0};
    #pragma unroll
    for (int i = 0; i < BT; ++i) {
        float xv = xs[i * 64 + dl];
        #pragma unroll
        for (int j = 0; j < 4; ++j) {
            float t2 = fmaf(-Li[j], gi[j], xv);
            float nr = fmaf(Lr[j], gr[j], t2);
            gi[j] = fmaf(Lr[j], gi[j], Li[j] * gr[j]);
            gr[j] = nr;
        }
    }
    #pragma unroll
    for (int j = 0; j < 4; ++j) {
        int n = q * 4 + j;
        s2[((size_t)bc * N + n) * D + d] = make_float2(gr[j], gi[j]);
    }
}

__global__ __launch_bounds__(256) void k_scan(
    const float* __restrict__ PTr, const float* __restrict__ PTi,
    float2* __restrict__ s2)
{
    const int tid = blockIdx.x * 256 + threadIdx.x;
    const float Lr = PTr[tid], Li = PTi[tid];
    float cr = 0.0f, ci = 0.0f;
    for (int c0 = 0; c0 < BNC; c0 += 16) {
        float2 sv[16];
        #pragma unroll
        for (int u = 0; u < 16; ++u)
            sv[u] = s2[(size_t)(c0 + u) * (N * D) + tid];
        #pragma unroll
        for (int u = 0; u < 16; ++u) {
            s2[(size_t)(c0 + u) * (N * D) + tid] = make_float2(cr, ci);
            float nr = fmaf(Lr, cr, fmaf(-Li, ci, sv[u].x));
            ci = fmaf(Lr, ci, fmaf(Li, cr, sv[u].y));
            cr = nr;
        }
    }
}

__global__ __launch_bounds__(256, 4) void k_out(
    const float* __restrict__ x,
    const float* __restrict__ PLr, const float* __restrict__ PLi,
    const float* __restrict__ PCr, const float* __restrict__ PCi,
    const float* __restrict__ Dp,
    const float2* __restrict__ s2,
    float* __restrict__ out)
{
    __shared__ float xs[BT * 64];
    const int bc = blockIdx.x >> 4;
    const int dg = blockIdx.x & 15;
    const int tid = threadIdx.x;
    const float* xg = x + (size_t)bc * BT * D + dg * 64;
    #pragma unroll
    for (int it = 0; it < 2; ++it) {
        int f = tid * 4 + it * 1024;
        int row = f >> 6, col = f & 63;
        *(float4*)&xs[row * 64 + col] = *(const float4*)(xg + (size_t)row * D + col);
    }
    const int q = tid & 3, dl = tid >> 2;
    const int d = dg * 64 + dl;
    float Lr[4], Li[4], Cr[4], Ci[4], gr[4], gi[4];
    #pragma unroll
    for (int j = 0; j < 4; ++j) {
        int n = q * 4 + j;
        Lr[j] = PLr[n * D + d];
        Li[j] = PLi[n * D + d];
        Cr[j] = PCr[n * D + d];
        Ci[j] = PCi[n * D + d];
        float2 cv = s2[((size_t)bc * N + n) * D + d];
        gr[j] = cv.x; gi[j] = cv.y;
    }
    const float dpv = Dp[d];
    float* og = out + (size_t)bc * BT * D + dg * 64;
    __syncthreads();
    #pragma unroll
    for (int ib = 0; ib < BT / 4; ++ib) {
        float keep = 0.0f;
        #pragma unroll
        for (int u = 0; u < 4; ++u) {
            int i = ib * 4 + u;
            float xv = xs[i * 64 + dl];
            float acc = 0.0f;
            #pragma unroll
            for (int j = 0; j < 4; ++j) {
                float t2 = fmaf(-Li[j], gi[j], xv);
                float nr = fmaf(Lr[j], gr[j], t2);
                gi[j] = fmaf(Lr[j], gi[j], Li[j] * gr[j]);
                gr[j] = nr;
                acc = fmaf(Cr[j], gr[j], acc);
                acc = fmaf(-Ci[j], gi[j], acc);
            }
            acc += __shfl_xor(acc, 1);
            acc += __shfl_xor(acc, 2);
            acc = fmaf(dpv, xv, acc);
            keep = (q == u) ? acc : keep;
        }
        og[(size_t)(ib * 4 + q) * D + dl] = keep;
    }
}

extern "C" void kernel_launch(void* const* d_in, const int* in_sizes, int n_in,
                              void* d_out, int out_size, void* d_ws, size_t ws_size,
                              hipStream_t stream) {
    const float* x     = (const float*)d_in[0];
    const float* Delta = (const float*)d_in[1];
    const float* A_re  = (const float*)d_in[2];
    const float* A_im  = (const float*)d_in[3];
    const float* B_re  = (const float*)d_in[4];
    const float* B_im  = (const float*)d_in[5];
    const float* C_re  = (const float*)d_in[6];
    const float* C_im  = (const float*)d_in[7];
    const float* Dp    = (const float*)d_in[8];
    float* out = (float*)d_out;
    float2* s2 = (float2*)d_ws;   // fused: FNC*N*D float2 = 8 MiB

    void* args[] = {(void*)&x, (void*)&Delta, (void*)&A_re, (void*)&A_im,
                    (void*)&B_re, (void*)&B_im, (void*)&C_re, (void*)&C_im,
                    (void*)&Dp, (void*)&out, (void*)&s2};
    hipError_t err = hipLaunchCooperativeKernel((const void*)k_fused,
                                                dim3(FNB), dim3(256),
                                                args, 0, stream);
    if (err != hipSuccess) {
        // Fallback: proven 4-kernel pipeline (NC=128)
        float* pbase = (float*)((char*)d_ws + (size_t)BNC * N * D * sizeof(float2));
        float* PLr = pbase + 0 * (N * D);
        float* PLi = pbase + 1 * (N * D);
        float* PTr = pbase + 2 * (N * D);
        float* PTi = pbase + 3 * (N * D);
        float* PCr = pbase + 4 * (N * D);
        float* PCi = pbase + 5 * (N * D);
        k_pre<<<(N * D) / 256, 256, 0, stream>>>(Delta, A_re, A_im, B_re, B_im,
                                                 C_re, C_im, PLr, PLi, PTr, PTi,
                                                 PCr, PCi);
        k_local<<<BNC * (D / 64), 256, 0, stream>>>(x, PLr, PLi, s2);
        k_scan<<<(N * D) / 256, 256, 0, stream>>>(PTr, PTi, s2);
        k_out<<<BNC * (D / 64), 256, 0, stream>>>(x, PLr, PLi, PCr, PCi, Dp,
                                                  s2, out);
    }
}

// Round 7
// 111.312 us; speedup vs baseline: 3.0259x; 3.0259x over previous
//
#include <hip/hip_runtime.h>
#include <math.h>

// Problem constants
constexpr int L  = 4096;    // seq len
constexpr int D  = 1024;    // d_model
constexpr int N  = 16;      // hiddens per channel
constexpr int NC = 64;      // chunks
constexpr int T  = L / NC;  // 64 steps per chunk
constexpr int DG = 64;      // channels per block
constexpr int G  = D / DG;  // 16 d-groups

__device__ __forceinline__ float softplus_f(float v) {
    return fmaxf(v, 0.0f) + log1pf(expf(-fabsf(v)));
}

// Fast Lambda = exp(dt*(ar + i*ai)) via HW transcendentals.
__device__ __forceinline__ void lam_fast(float ar, float ai, float dt,
                                         float& lr, float& li) {
    float e = __expf(ar * dt);
    float s, c;
    __sincosf(ai * dt, &s, &c);
    lr = e * c;
    li = e * s;
}

// K1: thread = (c, d, q): 4 states (n = q*4+j). Local scan, zero init.
// x staged via LDS. End states -> s2[c][n][d] (coalesced).
__global__ __launch_bounds__(256, 4) void k_local(
    const float* __restrict__ x,
    const float* __restrict__ Delta,
    const float* __restrict__ A_re, const float* __restrict__ A_im,
    float2* __restrict__ s2)
{
    __shared__ float xs[T * DG];          // 16 KiB
    const int c  = blockIdx.x >> 4;       // chunk
    const int dg = blockIdx.x & 15;       // d-group
    const int t  = threadIdx.x;

    const float* xg = x + (size_t)c * T * D + dg * DG;
    #pragma unroll
    for (int it = 0; it < 4; ++it) {      // 4096 floats, float4-coalesced
        int f = t * 4 + it * 1024;
        int row = f >> 6, col = f & 63;
        *(float4*)&xs[row * DG + col] =
            *(const float4*)(xg + (size_t)row * D + col);
    }

    const int q = t & 3, dl = t >> 2;
    const int d = dg * DG + dl;
    const float dt = softplus_f(Delta[d]);
    float Lr[4], Li[4];
    {
        float4 a0 = *(const float4*)(A_re + d * N + q * 4);
        float4 a1 = *(const float4*)(A_im + d * N + q * 4);
        const float ar[4] = {a0.x, a0.y, a0.z, a0.w};
        const float ai[4] = {a1.x, a1.y, a1.z, a1.w};
        #pragma unroll
        for (int j = 0; j < 4; ++j) lam_fast(ar[j], ai[j], dt, Lr[j], Li[j]);
    }
    __syncthreads();

    float gr[4] = {0, 0, 0, 0}, gi[4] = {0, 0, 0, 0};
    #pragma unroll
    for (int i = 0; i < T; ++i) {
        float xv = xs[i * DG + dl];
        #pragma unroll
        for (int j = 0; j < 4; ++j) {
            float t2 = fmaf(-Li[j], gi[j], xv);
            float nr = fmaf(Lr[j], gr[j], t2);
            gi[j] = fmaf(Lr[j], gi[j], Li[j] * gr[j]);
            gr[j] = nr;
        }
    }
    #pragma unroll
    for (int j = 0; j < 4; ++j)
        s2[((size_t)c * N + q * 4 + j) * D + d] = make_float2(gr[j], gi[j]);
}

// K2: thread = (n,d): serial scan over NC chunk states, in-place -> carry
// before each chunk. Batched 16-deep loads.
__global__ __launch_bounds__(256) void k_scan(
    const float* __restrict__ Delta,
    const float* __restrict__ A_re, const float* __restrict__ A_im,
    float2* __restrict__ s2)
{
    const int tid = blockIdx.x * 256 + threadIdx.x;  // n*D + d
    const int d = tid & (D - 1);
    const int n = tid >> 10;

    const float dt = softplus_f(Delta[d]);
    float Lr, Li;
    lam_fast(A_re[d * N + n], A_im[d * N + n], dt, Lr, Li);
    #pragma unroll
    for (int k = 0; k < 6; ++k) {         // Lam^64
        float nr = Lr * Lr - Li * Li;
        Li = 2.0f * Lr * Li;
        Lr = nr;
    }

    float cr = 0.0f, ci = 0.0f;
    #pragma unroll
    for (int c0 = 0; c0 < NC; c0 += 16) {
        float2 sv[16];
        #pragma unroll
        for (int u = 0; u < 16; ++u)
            sv[u] = s2[(size_t)(c0 + u) * (N * D) + tid];
        #pragma unroll
        for (int u = 0; u < 16; ++u) {
            s2[(size_t)(c0 + u) * (N * D) + tid] = make_float2(cr, ci);
            float nr = fmaf(Lr, cr, fmaf(-Li, ci, sv[u].x));
            ci = fmaf(Lr, ci, fmaf(Li, cr, sv[u].y));
            cr = nr;
        }
    }
}

// K3: thread = (c, d, q): re-run scan from carry for 4 states, contract with
// C' = dt*C*B, butterfly-reduce over q, add D*x, full-lane rotated stores.
__global__ __launch_bounds__(256, 4) void k_out(
    const float* __restrict__ x,
    const float* __restrict__ Delta,
    const float* __restrict__ A_re, const float* __restrict__ A_im,
    const float* __restrict__ B_re, const float* __restrict__ B_im,
    const float* __restrict__ C_re, const float* __restrict__ C_im,
    const float* __restrict__ Dp,
    const float2* __restrict__ s2,
    float* __restrict__ out)
{
    __shared__ float xs[T * DG];
    const int c  = blockIdx.x >> 4;
    const int dg = blockIdx.x & 15;
    const int t  = threadIdx.x;

    const float* xg = x + (size_t)c * T * D + dg * DG;
    #pragma unroll
    for (int it = 0; it < 4; ++it) {
        int f = t * 4 + it * 1024;
        int row = f >> 6, col = f & 63;
        *(float4*)&xs[row * DG + col] =
            *(const float4*)(xg + (size_t)row * D + col);
    }

    const int q = t & 3, dl = t >> 2;
    const int d = dg * DG + dl;
    const float dt  = softplus_f(Delta[d]);
    const float dpv = Dp[d];

    float Lr[4], Li[4], Cr[4], Ci[4], gr[4], gi[4];
    {
        const int pidx = d * N + q * 4;
        float4 a0 = *(const float4*)(A_re + pidx);
        float4 a1 = *(const float4*)(A_im + pidx);
        float4 b0 = *(const float4*)(B_re + pidx);
        float4 b1 = *(const float4*)(B_im + pidx);
        float4 c0 = *(const float4*)(C_re + pidx);
        float4 c1 = *(const float4*)(C_im + pidx);
        const float ar[4] = {a0.x, a0.y, a0.z, a0.w};
        const float ai[4] = {a1.x, a1.y, a1.z, a1.w};
        const float br[4] = {b0.x, b0.y, b0.z, b0.w};
        const float bi[4] = {b1.x, b1.y, b1.z, b1.w};
        const float crr[4] = {c0.x, c0.y, c0.z, c0.w};
        const float cii[4] = {c1.x, c1.y, c1.z, c1.w};
        #pragma unroll
        for (int j = 0; j < 4; ++j) {
            lam_fast(ar[j], ai[j], dt, Lr[j], Li[j]);
            Cr[j] = dt * (crr[j] * br[j] - cii[j] * bi[j]);
            Ci[j] = dt * (crr[j] * bi[j] + cii[j] * br[j]);
        }
    }
    #pragma unroll
    for (int j = 0; j < 4; ++j) {
        float2 cv = s2[((size_t)c * N + q * 4 + j) * D + d];
        gr[j] = cv.x; gi[j] = cv.y;
    }
    float* og = out + (size_t)c * T * D + dg * DG;
    __syncthreads();

    #pragma unroll
    for (int ib = 0; ib < T / 4; ++ib) {
        float keep = 0.0f;
        #pragma unroll
        for (int u = 0; u < 4; ++u) {
            int i = ib * 4 + u;
            float xv = xs[i * DG + dl];
            float acc = 0.0f;
            #pragma unroll
            for (int j = 0; j < 4; ++j) {
                float t2 = fmaf(-Li[j], gi[j], xv);
                float nr = fmaf(Lr[j], gr[j], t2);
                gi[j] = fmaf(Lr[j], gi[j], Li[j] * gr[j]);
                gr[j] = nr;
                acc = fmaf(Cr[j], gr[j], acc);
                acc = fmaf(-Ci[j], gi[j], acc);
            }
            acc += __shfl_xor(acc, 1);    // reduce over q-pairs
            acc += __shfl_xor(acc, 2);
            acc = fmaf(dpv, xv, acc);     // every lane has the full sum
            keep = (q == u) ? acc : keep; // lane q keeps iteration u==q
        }
        og[(size_t)(ib * 4 + q) * D + dl] = keep;  // all 64 lanes store
    }
}

extern "C" void kernel_launch(void* const* d_in, const int* in_sizes, int n_in,
                              void* d_out, int out_size, void* d_ws, size_t ws_size,
                              hipStream_t stream) {
    const float* x     = (const float*)d_in[0];
    const float* Delta = (const float*)d_in[1];
    const float* A_re  = (const float*)d_in[2];
    const float* A_im  = (const float*)d_in[3];
    const float* B_re  = (const float*)d_in[4];
    const float* B_im  = (const float*)d_in[5];
    const float* C_re  = (const float*)d_in[6];
    const float* C_im  = (const float*)d_in[7];
    const float* Dp    = (const float*)d_in[8];
    float* out = (float*)d_out;
    float2* s2 = (float2*)d_ws;   // NC * N * D float2 = 8 MiB

    k_local<<<NC * G, 256, 0, stream>>>(x, Delta, A_re, A_im, s2);
    k_scan<<<(N * D) / 256, 256, 0, stream>>>(Delta, A_re, A_im, s2);
    k_out<<<NC * G, 256, 0, stream>>>(x, Delta, A_re, A_im, B_re, B_im,
                                      C_re, C_im, Dp, s2, out);
}

// Round 8
// 108.484 us; speedup vs baseline: 3.1048x; 1.0261x over previous
//
#include <hip/hip_runtime.h>
#include <math.h>

// Problem constants
constexpr int L  = 4096;    // seq len
constexpr int D  = 1024;    // d_model
constexpr int N  = 16;      // hiddens per channel
constexpr int NC = 64;      // chunks
constexpr int T  = L / NC;  // 64 steps per chunk
constexpr int DG = 64;      // channels per block
constexpr int G  = D / DG;  // 16 d-groups

__device__ __forceinline__ float softplus_f(float v) {
    return fmaxf(v, 0.0f) + log1pf(expf(-fabsf(v)));
}

// Fast Lambda = exp(dt*(ar + i*ai)) via HW transcendentals.
__device__ __forceinline__ void lam_fast(float ar, float ai, float dt,
                                         float& lr, float& li) {
    float e = __expf(ar * dt);
    float s, c;
    __sincosf(ai * dt, &s, &c);
    lr = e * c;
    li = e * s;
}

// K1: thread = (c, d, q): 4 states (n = q*4+j). Local scan, zero init.
// x staged via LDS. End states -> s2[c][n][d] (coalesced).
__global__ __launch_bounds__(256, 4) void k_local(
    const float* __restrict__ x,
    const float* __restrict__ Delta,
    const float* __restrict__ A_re, const float* __restrict__ A_im,
    float2* __restrict__ s2)
{
    __shared__ float xs[T * DG];          // 16 KiB
    const int c  = blockIdx.x >> 4;       // chunk
    const int dg = blockIdx.x & 15;       // d-group
    const int t  = threadIdx.x;

    const float* xg = x + (size_t)c * T * D + dg * DG;
    #pragma unroll
    for (int it = 0; it < 4; ++it) {      // 4096 floats, float4-coalesced
        int f = t * 4 + it * 1024;
        int row = f >> 6, col = f & 63;
        *(float4*)&xs[row * DG + col] =
            *(const float4*)(xg + (size_t)row * D + col);
    }

    const int q = t & 3, dl = t >> 2;
    const int d = dg * DG + dl;
    const float dt = softplus_f(Delta[d]);
    float Lr[4], Li[4];
    {
        float4 a0 = *(const float4*)(A_re + d * N + q * 4);
        float4 a1 = *(const float4*)(A_im + d * N + q * 4);
        const float ar[4] = {a0.x, a0.y, a0.z, a0.w};
        const float ai[4] = {a1.x, a1.y, a1.z, a1.w};
        #pragma unroll
        for (int j = 0; j < 4; ++j) lam_fast(ar[j], ai[j], dt, Lr[j], Li[j]);
    }
    __syncthreads();

    float gr[4] = {0, 0, 0, 0}, gi[4] = {0, 0, 0, 0};
    #pragma unroll
    for (int i = 0; i < T; ++i) {
        float xv = xs[i * DG + dl];
        #pragma unroll
        for (int j = 0; j < 4; ++j) {
            float t2 = fmaf(-Li[j], gi[j], xv);
            float nr = fmaf(Lr[j], gr[j], t2);
            gi[j] = fmaf(Lr[j], gi[j], Li[j] * gr[j]);
            gr[j] = nr;
        }
    }
    #pragma unroll
    for (int j = 0; j < 4; ++j)
        s2[((size_t)c * N + q * 4 + j) * D + d] = make_float2(gr[j], gi[j]);
}

// K2: thread = (n,d): serial scan over NC chunk states, in-place -> carry
// before each chunk. Grid = 256 blocks x 64 threads: one wave per CU so the
// 16 MB of state traffic is spread over ALL CUs' memory queues (the 64-block
// version concentrated it on 25% of the machine). Batch 32-deep: 2 serial
// latency episodes.
__global__ __launch_bounds__(64) void k_scan(
    const float* __restrict__ Delta,
    const float* __restrict__ A_re, const float* __restrict__ A_im,
    float2* __restrict__ s2)
{
    const int tid = blockIdx.x * 64 + threadIdx.x;   // n*D + d
    const int d = tid & (D - 1);
    const int n = tid >> 10;

    const float dt = softplus_f(Delta[d]);
    float Lr, Li;
    lam_fast(A_re[d * N + n], A_im[d * N + n], dt, Lr, Li);
    #pragma unroll
    for (int k = 0; k < 6; ++k) {         // Lam^64
        float nr = Lr * Lr - Li * Li;
        Li = 2.0f * Lr * Li;
        Lr = nr;
    }

    float cr = 0.0f, ci = 0.0f;
    #pragma unroll
    for (int c0 = 0; c0 < NC; c0 += 32) {
        float2 sv[32];
        #pragma unroll
        for (int u = 0; u < 32; ++u)
            sv[u] = s2[(size_t)(c0 + u) * (N * D) + tid];
        #pragma unroll
        for (int u = 0; u < 32; ++u) {
            s2[(size_t)(c0 + u) * (N * D) + tid] = make_float2(cr, ci);
            float nr = fmaf(Lr, cr, fmaf(-Li, ci, sv[u].x));
            ci = fmaf(Lr, ci, fmaf(Li, cr, sv[u].y));
            cr = nr;
        }
    }
}

// K3: thread = (c, d, q): re-run scan from carry for 4 states, contract with
// C' = dt*C*B, butterfly-reduce over q, add D*x, full-lane rotated stores.
__global__ __launch_bounds__(256, 4) void k_out(
    const float* __restrict__ x,
    const float* __restrict__ Delta,
    const float* __restrict__ A_re, const float* __restrict__ A_im,
    const float* __restrict__ B_re, const float* __restrict__ B_im,
    const float* __restrict__ C_re, const float* __restrict__ C_im,
    const float* __restrict__ Dp,
    const float2* __restrict__ s2,
    float* __restrict__ out)
{
    __shared__ float xs[T * DG];
    const int c  = blockIdx.x >> 4;
    const int dg = blockIdx.x & 15;
    const int t  = threadIdx.x;

    const float* xg = x + (size_t)c * T * D + dg * DG;
    #pragma unroll
    for (int it = 0; it < 4; ++it) {
        int f = t * 4 + it * 1024;
        int row = f >> 6, col = f & 63;
        *(float4*)&xs[row * DG + col] =
            *(const float4*)(xg + (size_t)row * D + col);
    }

    const int q = t & 3, dl = t >> 2;
    const int d = dg * DG + dl;
    const float dt  = softplus_f(Delta[d]);
    const float dpv = Dp[d];

    float Lr[4], Li[4], Cr[4], Ci[4], gr[4], gi[4];
    {
        const int pidx = d * N + q * 4;
        float4 a0 = *(const float4*)(A_re + pidx);
        float4 a1 = *(const float4*)(A_im + pidx);
        float4 b0 = *(const float4*)(B_re + pidx);
        float4 b1 = *(const float4*)(B_im + pidx);
        float4 c0 = *(const float4*)(C_re + pidx);
        float4 c1 = *(const float4*)(C_im + pidx);
        const float ar[4] = {a0.x, a0.y, a0.z, a0.w};
        const float ai[4] = {a1.x, a1.y, a1.z, a1.w};
        const float br[4] = {b0.x, b0.y, b0.z, b0.w};
        const float bi[4] = {b1.x, b1.y, b1.z, b1.w};
        const float crr[4] = {c0.x, c0.y, c0.z, c0.w};
        const float cii[4] = {c1.x, c1.y, c1.z, c1.w};
        #pragma unroll
        for (int j = 0; j < 4; ++j) {
            lam_fast(ar[j], ai[j], dt, Lr[j], Li[j]);
            Cr[j] = dt * (crr[j] * br[j] - cii[j] * bi[j]);
            Ci[j] = dt * (crr[j] * bi[j] + cii[j] * br[j]);
        }
    }
    #pragma unroll
    for (int j = 0; j < 4; ++j) {
        float2 cv = s2[((size_t)c * N + q * 4 + j) * D + d];
        gr[j] = cv.x; gi[j] = cv.y;
    }
    float* og = out + (size_t)c * T * D + dg * DG;
    __syncthreads();

    #pragma unroll
    for (int ib = 0; ib < T / 4; ++ib) {
        float keep = 0.0f;
        #pragma unroll
        for (int u = 0; u < 4; ++u) {
            int i = ib * 4 + u;
            float xv = xs[i * DG + dl];
            float acc = 0.0f;
            #pragma unroll
            for (int j = 0; j < 4; ++j) {
                float t2 = fmaf(-Li[j], gi[j], xv);
                float nr = fmaf(Lr[j], gr[j], t2);
                gi[j] = fmaf(Lr[j], gi[j], Li[j] * gr[j]);
                gr[j] = nr;
                acc = fmaf(Cr[j], gr[j], acc);
                acc = fmaf(-Ci[j], gi[j], acc);
            }
            acc += __shfl_xor(acc, 1);    // reduce over q-pairs
            acc += __shfl_xor(acc, 2);
            acc = fmaf(dpv, xv, acc);     // every lane has the full sum
            keep = (q == u) ? acc : keep; // lane q keeps iteration u==q
        }
        og[(size_t)(ib * 4 + q) * D + dl] = keep;  // all 64 lanes store
    }
}

extern "C" void kernel_launch(void* const* d_in, const int* in_sizes, int n_in,
                              void* d_out, int out_size, void* d_ws, size_t ws_size,
                              hipStream_t stream) {
    const float* x     = (const float*)d_in[0];
    const float* Delta = (const float*)d_in[1];
    const float* A_re  = (const float*)d_in[2];
    const float* A_im  = (const float*)d_in[3];
    const float* B_re  = (const float*)d_in[4];
    const float* B_im  = (const float*)d_in[5];
    const float* C_re  = (const float*)d_in[6];
    const float* C_im  = (const float*)d_in[7];
    const float* Dp    = (const float*)d_in[8];
    float* out = (float*)d_out;
    float2* s2 = (float2*)d_ws;   // NC * N * D float2 = 8 MiB

    k_local<<<NC * G, 256, 0, stream>>>(x, Delta, A_re, A_im, s2);
    k_scan<<<(N * D) / 64, 64, 0, stream>>>(Delta, A_re, A_im, s2);
    k_out<<<NC * G, 256, 0, stream>>>(x, Delta, A_re, A_im, B_re, B_im,
                                      C_re, C_im, Dp, s2, out);
}